// Round 2
// baseline (1957.338 us; speedup 1.0000x reference)
//
#include <hip/hip_runtime.h>
#include <hip/hip_bf16.h>
#include <cstdint>

typedef unsigned short u16;
typedef __bf16 bf16x8 __attribute__((ext_vector_type(8)));
typedef float floatx4 __attribute__((ext_vector_type(4)));

// ---- helpers ----------------------------------------------------------------

__device__ __forceinline__ u16 f2bf(float f) {
    union { float f; uint32_t u; } x; x.f = f;
    uint32_t u = x.u;
    u = (u + 0x7FFFu + ((u >> 16) & 1u)) >> 16;   // RNE
    return (u16)u;
}

__device__ __forceinline__ float bf2f(u16 b) {
    union { uint32_t u; float f; } x; x.u = ((uint32_t)b) << 16;
    return x.f;
}

// async global->LDS, 16B per lane; LDS dest is wave-uniform base + lane*16.
// NOTE: direct C-style casts -> clang emits proper addrspacecast (the
// uintptr_t round-trip used before produced garbage LDS offsets).
__device__ __forceinline__ void load16_to_lds(const u16* g, u16* l) {
    __builtin_amdgcn_global_load_lds(
        (const __attribute__((address_space(1))) unsigned int*)g,
        (__attribute__((address_space(3))) unsigned int*)l, 16, 0, 0);
}

// ---- pack / cast: fp32 [src_rows,src_cols] -> bf16 [pad_rows,pad_cols] at
// dst[row*dst_stride + dst_off + col], zero-filling the pad region ------------

__global__ void pack_pad(const float* __restrict__ src, u16* __restrict__ dst,
                         int src_rows, int src_cols, int pad_cols,
                         int dst_stride, int dst_off, long total) {
    long i = (long)blockIdx.x * blockDim.x + threadIdx.x;
    if (i >= total) return;
    int  col = (int)(i % pad_cols);
    long row = i / pad_cols;
    float v = (row < src_rows && col < src_cols) ? src[row * (long)src_cols + col] : 0.f;
    dst[row * (long)dst_stride + dst_off + col] = f2bf(v);
}

// ---- router: logits = x @ gate_w^T, fp32, one wave per token ----------------

__global__ void router_kernel(const float* __restrict__ x,
                              const float* __restrict__ gw,
                              float* __restrict__ out) {
    const int t = blockIdx.x;
    const int lane = threadIdx.x;            // 0..63
    const float* xr = x + (long)t * 2048;
    float acc[8] = {0.f,0.f,0.f,0.f,0.f,0.f,0.f,0.f};
    for (int k = lane; k < 2048; k += 64) {
        float xv = xr[k];
        #pragma unroll
        for (int e = 0; e < 8; e++) acc[e] += xv * gw[e * 2048 + k];
    }
    #pragma unroll
    for (int off = 32; off > 0; off >>= 1) {
        #pragma unroll
        for (int e = 0; e < 8; e++) acc[e] += __shfl_down(acc[e], off, 64);
    }
    if (lane == 0) {
        #pragma unroll
        for (int e = 0; e < 8; e++) out[(long)t * 8 + e] = acc[e];
    }
}

// ---- bf16 GEMM, C[M,N] = A[M,K] @ B[N,K]^T, 128x128 tile, BK=32, m97-style --
// EPI: 0 = fp32 store, 1 = bf16 store, 2 = bf16 store of silu(acc)*Mul,
//      3 = fp32 accumulate (C += acc)

template <int EPI>
__global__ __launch_bounds__(256)
void gemm_bt(const u16* __restrict__ A, int lda,
             const u16* __restrict__ B, int ldb,
             void* __restrict__ C, int ldc,
             const u16* __restrict__ Mul, int ldmul,
             int K) {
    __shared__ u16 sA[128 * 32];
    __shared__ u16 sB[128 * 32];

    const int tid  = threadIdx.x;
    const int wave = tid >> 6;
    const int lane = tid & 63;
    const int l15  = lane & 15;
    const int lq   = lane >> 4;          // 0..3
    const int wm   = wave >> 1;          // 0..1
    const int wn   = wave & 1;           // 0..1
    const long rowBase = (long)blockIdx.y * 128;
    const long colBase = (long)blockIdx.x * 128;

    floatx4 acc[4][4] = {};

    // staging: 512 chunks of 8 elems per tile; thread handles lin = i*256+tid
    const u16* gA[2]; const u16* gB[2];
    u16* lA[2]; u16* lB[2];
    #pragma unroll
    for (int i = 0; i < 2; i++) {
        int lin = i * 256 + tid;
        int row = lin >> 2;
        int kc  = lin & 3;
        gA[i] = A + (rowBase + row) * (long)lda + kc * 8;
        gB[i] = B + (colBase + row) * (long)ldb + kc * 8;
        int base = (i * 256 + wave * 64) * 8;   // wave-uniform element base
        lA[i] = &sA[base];
        lB[i] = &sB[base];
    }

    const int nk = K >> 5;
    for (int kt = 0; kt < nk; kt++) {
        const int ko = kt * 32;
        #pragma unroll
        for (int i = 0; i < 2; i++) {
            load16_to_lds(gA[i] + ko, lA[i]);
            load16_to_lds(gB[i] + ko, lB[i]);
        }
        __syncthreads();

        bf16x8 af[4], bb[4];
        #pragma unroll
        for (int i = 0; i < 4; i++)
            af[i] = *(const bf16x8*)&sA[(wm * 64 + i * 16 + l15) * 32 + lq * 8];
        #pragma unroll
        for (int j = 0; j < 4; j++)
            bb[j] = *(const bf16x8*)&sB[(wn * 64 + j * 16 + l15) * 32 + lq * 8];
        #pragma unroll
        for (int i = 0; i < 4; i++)
            #pragma unroll
            for (int j = 0; j < 4; j++)
                acc[i][j] = __builtin_amdgcn_mfma_f32_16x16x32_bf16(af[i], bb[j], acc[i][j], 0, 0, 0);
        __syncthreads();
    }

    // epilogue: C/D layout col = lane&15, row = (lane>>4)*4 + reg
    #pragma unroll
    for (int i = 0; i < 4; i++) {
        long row0 = rowBase + wm * 64 + i * 16 + lq * 4;
        #pragma unroll
        for (int j = 0; j < 4; j++) {
            long col = colBase + wn * 64 + j * 16 + l15;
            #pragma unroll
            for (int r = 0; r < 4; r++) {
                float v = acc[i][j][r];
                long idx = (row0 + r) * (long)ldc + col;
                if (EPI == 0) {
                    ((float*)C)[idx] = v;
                } else if (EPI == 1) {
                    ((u16*)C)[idx] = f2bf(v);
                } else if (EPI == 2) {
                    float u = bf2f(Mul[(row0 + r) * (long)ldmul + col]);
                    float s = v / (1.f + __expf(-v));
                    ((u16*)C)[idx] = f2bf(s * u);
                } else {
                    ((float*)C)[idx] += v;
                }
            }
        }
    }
}

// ---- launch -----------------------------------------------------------------

static inline void launch_pack(const float* src, u16* dst, int sr, int sc,
                               int pr, int pc, int stride, int off,
                               hipStream_t stream) {
    long total = (long)pr * pc;
    int blocks = (int)((total + 255) / 256);
    hipLaunchKernelGGL(pack_pad, dim3(blocks), dim3(256), 0, stream,
                       src, dst, sr, sc, pc, stride, off, total);
}

extern "C" void kernel_launch(void* const* d_in, const int* in_sizes, int n_in,
                              void* d_out, int out_size, void* d_ws, size_t ws_size,
                              hipStream_t stream) {
    const float* x      = (const float*)d_in[0];   // [8192, 2048]
    const float* gate_w = (const float*)d_in[1];   // [8, 2048]
    const float* w1     = (const float*)d_in[2];   // [7168, 2048]
    const float* w2     = (const float*)d_in[3];   // [2048, 7168]
    const float* w3     = (const float*)d_in[4];   // [7168, 2048]
    const float* u1     = (const float*)d_in[5];   // [7168, 398]
    const float* v1     = (const float*)d_in[6];   // [398, 2048]
    const float* u2     = (const float*)d_in[7];   // [2048, 398]
    const float* v2     = (const float*)d_in[8];   // [398, 7168]
    const float* u3     = (const float*)d_in[9];   // [7168, 398]
    const float* v3     = (const float*)d_in[10];  // [398, 2048]

    float* out    = (float*)d_out;                 // [8192,2048] then [8192,8]
    float* logits = out + 16777216L;

    // ---- workspace layout (bf16 elems), peak 206.6 MB ----
    // XT [8192,3072] = [T3 | Xb | T1]; WR = shared weight region (phased);
    // UB [8192,7168] = up, then H in-place; T2 overlays dead XT.
    u16* XT = (u16*)d_ws;                  // 25,165,824 elems
    u16* WR = XT + 25165824L;              // 19,398,656 elems
    u16* UB = WR + 19398656L;              // 58,720,256 elems
    u16* T2 = XT;                          // [8192,512] after GEMM3 (XT dead)

    // phase A: WR = {v3p [512,2048] | v1p [512,2048]}
    u16* V3P = WR;
    u16* V1P = WR + 512L * 2048;
    // phase B: WR = WU [7168,2560] = [u3p | w3]
    u16* WU  = WR;
    // phase C: WR = WG [7168,2560] = [w1 | u1p]
    u16* WG  = WR;
    // phase D: WR = {v2p [512,7168] | w2b [2048,7168] | u2p [2048,512]}
    u16* V2P = WR;
    u16* W2B = WR + 512L * 7168;
    u16* U2P = W2B + 2048L * 7168;

    // ---- router (reads fp32 x directly; independent) ----
    hipLaunchKernelGGL(router_kernel, dim3(8192), dim3(64), 0, stream,
                       x, gate_w, logits);

    // ---- pack phase A ----
    launch_pack(x,  XT + 512, 8192, 2048, 8192, 2048, 3072, 0, stream);  // Xb
    launch_pack(v3, V3P, 398, 2048, 512, 2048, 2048, 0, stream);
    launch_pack(v1, V1P, 398, 2048, 512, 2048, 2048, 0, stream);

    // ---- GEMM1a: T3 = Xb @ v3p^T -> XT cols [0,512) ----
    hipLaunchKernelGGL((gemm_bt<1>), dim3(4, 64), dim3(256), 0, stream,
                       XT + 512, 3072, V3P, 2048, (void*)XT, 3072,
                       (const u16*)nullptr, 0, 2048);
    // ---- GEMM1b: T1 = Xb @ v1p^T -> XT cols [2560,3072) ----
    hipLaunchKernelGGL((gemm_bt<1>), dim3(4, 64), dim3(256), 0, stream,
                       XT + 512, 3072, V1P, 2048, (void*)(XT + 2560), 3072,
                       (const u16*)nullptr, 0, 2048);

    // ---- pack phase B: WU = [u3p | w3] ----
    launch_pack(u3, WU, 7168, 398, 7168, 512, 2560, 0, stream);
    launch_pack(w3, WU, 7168, 2048, 7168, 2048, 2560, 512, stream);

    // ---- GEMM2: UB = XT[:,0:2560] @ WU^T  (up = x@w3^T + t3@u3^T) ----
    hipLaunchKernelGGL((gemm_bt<1>), dim3(56, 64), dim3(256), 0, stream,
                       XT, 3072, WU, 2560, (void*)UB, 7168,
                       (const u16*)nullptr, 0, 2560);

    // ---- pack phase C: WG = [w1 | u1p] ----
    launch_pack(w1, WG, 7168, 2048, 7168, 2048, 2560, 0, stream);
    launch_pack(u1, WG, 7168, 398, 7168, 512, 2560, 2048, stream);

    // ---- GEMM3: UB = silu(XT[:,512:3072] @ WG^T) * UB  (H, in-place) ----
    hipLaunchKernelGGL((gemm_bt<2>), dim3(56, 64), dim3(256), 0, stream,
                       XT + 512, 3072, WG, 2560, (void*)UB, 7168,
                       UB, 7168, 2560);

    // ---- pack phase D: {v2p, w2b, u2p} ----
    launch_pack(v2, V2P, 398, 7168, 512, 7168, 7168, 0, stream);
    launch_pack(w2, W2B, 2048, 7168, 2048, 7168, 7168, 0, stream);
    launch_pack(u2, U2P, 2048, 398, 2048, 512, 512, 0, stream);

    // ---- GEMM4: T2 = H @ v2p^T  (into dead XT region) ----
    hipLaunchKernelGGL((gemm_bt<1>), dim3(4, 64), dim3(256), 0, stream,
                       UB, 7168, V2P, 7168, (void*)T2, 512,
                       (const u16*)nullptr, 0, 7168);

    // ---- GEMM5a: out = H @ w2b^T (fp32 store) ----
    hipLaunchKernelGGL((gemm_bt<0>), dim3(16, 64), dim3(256), 0, stream,
                       UB, 7168, W2B, 7168, (void*)out, 2048,
                       (const u16*)nullptr, 0, 7168);

    // ---- GEMM5b: out += T2 @ u2p^T (fp32 accumulate) ----
    hipLaunchKernelGGL((gemm_bt<3>), dim3(16, 64), dim3(256), 0, stream,
                       T2, 512, U2P, 512, (void*)out, 2048,
                       (const u16*)nullptr, 0, 512);
}